// Round 5
// baseline (90.320 us; speedup 1.0000x reference)
//
#include <hip/hip_runtime.h>

#define NPTS 1024
#define DIM 64
#define KNN 16
#define NA 12
#define NCOL 192              // (a,k) rows, idx = a*16 + k
#define XPAD 72               // u16 row stride: 144 B rows -> 16B-aligned b128 frags, 2-way banks

typedef __attribute__((ext_vector_type(8))) short bf16x8;
typedef __attribute__((ext_vector_type(4))) float f32x4;

static __device__ inline unsigned short f2bfu(float x) {
    __bf16 b = (__bf16)x;                       // hw v_cvt (RNE)
    return __builtin_bit_cast(unsigned short, b);
}
static __device__ inline float bf2f(unsigned short s) {
    return __uint_as_float(((unsigned)s) << 16);
}
static __device__ inline unsigned pk2(float lo, float hi) {
    return (unsigned)f2bfu(lo) | ((unsigned)f2bfu(hi) << 16);
}
static __device__ inline bf16x8 load8_cvt(const float* p) {
    f32x4 u = *(const f32x4*)p;
    f32x4 v = *(const f32x4*)(p + 4);
    bf16x8 r;
    r[0] = (short)f2bfu(u[0]); r[1] = (short)f2bfu(u[1]); r[2] = (short)f2bfu(u[2]); r[3] = (short)f2bfu(u[3]);
    r[4] = (short)f2bfu(v[0]); r[5] = (short)f2bfu(v[1]); r[6] = (short)f2bfu(v[2]); r[7] = (short)f2bfu(v[3]);
    return r;
}

// ---------------- prep kernel: qkv^T MFMA + weight frag packing + KNN (unchanged) ----------------
__global__ __launch_bounds__(256) void prep_kernel(const float* __restrict__ feats,
                                                   const float* __restrict__ to_qkv,
                                                   float* __restrict__ qkvT,
                                                   unsigned short* __restrict__ pack,
                                                   const float* __restrict__ pos2,
                                                   const float* __restrict__ am1,
                                                   const float* __restrict__ am2,
                                                   const float* __restrict__ xyz,
                                                   int* __restrict__ idxout) {
    __shared__ unsigned short XT[48][72];   // feats^T [na][i] bf16
    __shared__ float px[NPTS], py[NPTS], pz[NPTS];
    const int t = threadIdx.x;
    const int n0 = blockIdx.x * 48;

    // ---- weight frag packing (blocks 0..71, one frag-set each) ----
    if (blockIdx.x < 72 && t < 64) {
        int s = blockIdx.x;
        int c16p = t & 15, gp = t >> 4;
        const float* src;
        if (s < 8) {
            int nt = s >> 1, kt = s & 1;
            src = pos2 + (nt * 16 + c16p) * 64 + kt * 32 + gp * 8;
        } else if (s < 40) {
            int u = s - 8, hq = u >> 3, nt = (u >> 1) & 3, kt = u & 1;
            src = am1 + (hq * 64 + nt * 16 + c16p) * 64 + kt * 32 + gp * 8;
        } else {
            int u = s - 40, hq = u >> 3, nt = (u >> 1) & 3, kt = u & 1;
            src = am2 + (nt * 16 + c16p) * 256 + hq * 64 + kt * 32 + gp * 8;
        }
        unsigned short* dst = pack + (s * 64 + t) * 8;
        #pragma unroll
        for (int e = 0; e < 8; ++e) dst[e] = f2bfu(src[e]);
    }

    for (int m = t; m < NPTS; m += 256) {
        px[m] = xyz[m];
        py[m] = xyz[NPTS + m];
        pz[m] = xyz[2 * NPTS + m];
    }
    for (int e = t; e < 48 * 64; e += 256) {
        int c = e % 48, i = e / 48;
        XT[c][i] = f2bfu(feats[i * (NPTS * NA) + n0 + c]);
    }
    __syncthreads();

    const int lane = t & 63, w = t >> 6, c16 = lane & 15, g = lane >> 4;

    // ---- qkv: D[na][cd] = feats^T @ to_qkv^T ----
    {
        bf16x8 bfr[3][2];
        #pragma unroll
        for (int ni = 0; ni < 3; ++ni)
            #pragma unroll
            for (int kt = 0; kt < 2; ++kt) {
                int cd = (w * 3 + ni) * 16 + c16;
                bfr[ni][kt] = load8_cvt(to_qkv + cd * 64 + kt * 32 + g * 8);
            }
        const f32x4 zero4 = {0.f, 0.f, 0.f, 0.f};
        #pragma unroll
        for (int mt = 0; mt < 3; ++mt) {
            f32x4 acc[3] = {zero4, zero4, zero4};
            #pragma unroll
            for (int kt = 0; kt < 2; ++kt) {
                bf16x8 af = *(const bf16x8*)&XT[mt * 16 + c16][kt * 32 + g * 8];
                #pragma unroll
                for (int ni = 0; ni < 3; ++ni)
                    acc[ni] = __builtin_amdgcn_mfma_f32_16x16x32_bf16(af, bfr[ni][kt], acc[ni], 0, 0, 0);
            }
            #pragma unroll
            for (int ni = 0; ni < 3; ++ni) {
                int cd = (w * 3 + ni) * 16 + c16;
                int c = cd >> 6, d = cd & 63;
                #pragma unroll
                for (int r = 0; r < 4; ++r) {
                    int na = n0 + mt * 16 + 4 * g + r;
                    qkvT[c * (NPTS * NA * DIM) + na * 64 + d] = acc[ni][r];
                }
            }
        }
    }

    // ---- knn: one wave per point, 4 points per block ----
    {
        const int n = blockIdx.x * 4 + w;
        const float xn = px[n], yn = py[n], zn = pz[n];
        const float sqn = xn * xn + yn * yn + zn * zn;
        float dd[16]; int id[16];
        #pragma unroll
        for (int j = 0; j < 16; ++j) {
            int m = j * 64 + lane;
            float xm = px[m], ym = py[m], zm = pz[m];
            float sqm = xm * xm + ym * ym + zm * zm;
            float dot = xn * xm + yn * ym + zn * zm;
            dd[j] = sqn + sqm - 2.f * dot;
            id[j] = m;
        }
        for (int r = 0; r < KNN; ++r) {
            float bd = 1e30f; int bi = 0x7fffffff;
            #pragma unroll
            for (int j = 0; j < 16; ++j)
                if (dd[j] < bd || (dd[j] == bd && id[j] < bi)) { bd = dd[j]; bi = id[j]; }
            #pragma unroll
            for (int mask = 1; mask < 64; mask <<= 1) {
                float od = __shfl_xor(bd, mask);
                int oi = __shfl_xor(bi, mask);
                if (od < bd || (od == bd && oi < bi)) { bd = od; bi = oi; }
            }
            if (lane == 0) idxout[n * KNN + r] = bi;
            #pragma unroll
            for (int j = 0; j < 16; ++j)
                if (id[j] == bi) dd[j] = 1e30f;
        }
    }
}

// ---------------- attn kernel: wave-private dataflow, zero mid-kernel barriers ----------------
// 6 waves; wave w owns anchors {2w, 2w+1} (rows 32w..32w+31 of the 192 (a,k) rows),
// computes full output width for its rows in every stage. All inter-stage transposes go
// through the wave's private 32-row LDS region -> wave-local lgkmcnt waits, no s_barrier.
// C layout per guide: lane(c16,g) reg r holds D[(a, k=4g+r)][out = nt*16+c16].
__global__ __launch_bounds__(384, 3) void attn_main(const float* __restrict__ xyz,
                                                    const float* __restrict__ pos1,
                                                    const float* __restrict__ anchors,
                                                    const unsigned short* __restrict__ pack,
                                                    const float* __restrict__ qT,
                                                    const float* __restrict__ kT,
                                                    const float* __restrict__ vT,
                                                    const int* __restrict__ nn,
                                                    float* __restrict__ out) {
    __shared__ float P1s[192];
    __shared__ float abs_s[108];
    __shared__ __align__(16) unsigned short Xw[6 * 32 * XPAD];   // per-wave 32-row region, X then Hq

    const int n = blockIdx.x, t = threadIdx.x;
    const int lane = t & 63, wave = t >> 6;
    const int c16 = lane & 15, g = lane >> 4;
    const int a0 = 2 * wave;

    if (t < 192) P1s[t] = pos1[t];
    if (t < 108) abs_s[t] = anchors[t];
    __syncthreads();                      // the only block barrier

    // ---- per-lane neighbor indices and rel vector ----
    int mk[4];
    #pragma unroll
    for (int r = 0; r < 4; ++r) mk[r] = nn[n * KNN + 4 * g + r];
    const int mc = nn[n * KNN + c16];
    const float relx = xyz[n] - xyz[mc];
    const float rely = xyz[NPTS + n] - xyz[NPTS + mc];
    const float relz = xyz[2 * NPTS + n] - xyz[2 * NPTS + mc];

    // ---- pe1 A-frags directly in registers: row (a, k=c16), cols h = kt*32+g*8+e ----
    float G[2][3];
    #pragma unroll
    for (int ai = 0; ai < 2; ++ai) {
        int a = a0 + ai;
        G[ai][0] = abs_s[a * 9 + 0] * relx + abs_s[a * 9 + 1] * rely + abs_s[a * 9 + 2] * relz;
        G[ai][1] = abs_s[a * 9 + 3] * relx + abs_s[a * 9 + 4] * rely + abs_s[a * 9 + 5] * relz;
        G[ai][2] = abs_s[a * 9 + 6] * relx + abs_s[a * 9 + 7] * rely + abs_s[a * 9 + 8] * relz;
    }
    bf16x8 pfrag[2][2];
    #pragma unroll
    for (int kt = 0; kt < 2; ++kt)
        #pragma unroll
        for (int e = 0; e < 8; ++e) {
            int h = kt * 32 + g * 8 + e;
            float p0 = P1s[3 * h], p1 = P1s[3 * h + 1], p2 = P1s[3 * h + 2];
            #pragma unroll
            for (int ai = 0; ai < 2; ++ai) {
                float p = p0 * G[ai][0] + p1 * G[ai][1] + p2 * G[ai][2];
                pfrag[ai][kt][e] = (short)f2bfu(fmaxf(p, 0.f));
            }
        }

    const bf16x8* pk16 = (const bf16x8*)pack;
    const f32x4 zero4 = {0.f, 0.f, 0.f, 0.f};

    // ---- phase 0: pe^T = pe1^T @ P2^T  (acc[ai][nt]) ----
    f32x4 acc[2][4];
    #pragma unroll
    for (int ai = 0; ai < 2; ++ai)
        #pragma unroll
        for (int nt = 0; nt < 4; ++nt) acc[ai][nt] = zero4;
    #pragma unroll
    for (int kt = 0; kt < 2; ++kt)
        #pragma unroll
        for (int nt = 0; nt < 4; ++nt) {
            bf16x8 bf = pk16[(nt * 2 + kt) * 64 + lane];
            acc[0][nt] = __builtin_amdgcn_mfma_f32_16x16x32_bf16(pfrag[0][kt], bf, acc[0][nt], 0, 0, 0);
            acc[1][nt] = __builtin_amdgcn_mfma_f32_16x16x32_bf16(pfrag[1][kt], bf, acc[1][nt], 0, 0, 0);
        }

    // ---- step 3: gathers; vg -> packed regs; X -> wave-private LDS (transpose) ----
    unsigned short* xw = Xw + wave * 32 * XPAD;
    unsigned vgp[2][4][2];
    #pragma unroll
    for (int ai = 0; ai < 2; ++ai) {
        int a = a0 + ai;
        #pragma unroll
        for (int nt = 0; nt < 4; ++nt) {
            int d = nt * 16 + c16;
            float qv = qT[(n * NA + a) * DIM + d];
            float xr[4], vg[4];
            #pragma unroll
            for (int r = 0; r < 4; ++r) {
                int b = (mk[r] * NA + a) * DIM + d;
                float pe = acc[ai][nt][r];
                xr[r] = qv - kT[b] + pe;
                vg[r] = vT[b] + pe;
            }
            vgp[ai][nt][0] = pk2(vg[0], vg[1]);
            vgp[ai][nt][1] = pk2(vg[2], vg[3]);
            #pragma unroll
            for (int r = 0; r < 4; ++r)
                xw[(ai * 16 + 4 * g + r) * XPAD + d] = f2bfu(xr[r]);
        }
    }
    __builtin_amdgcn_sched_barrier(0);
    asm volatile("s_waitcnt lgkmcnt(0)" ::: "memory");
    __builtin_amdgcn_sched_barrier(0);

    // X A-frags (live across all 4 rounds)
    bf16x8 xf[2][2];
    #pragma unroll
    for (int ai = 0; ai < 2; ++ai)
        #pragma unroll
        for (int kt = 0; kt < 2; ++kt)
            xf[ai][kt] = *(const bf16x8*)&xw[(ai * 16 + c16) * XPAD + kt * 32 + g * 8];

    // ---- 4 rounds: Hq^T = relu(X^T @ W1q^T); S^T += Hq^T @ W2q^T ----
    f32x4 sacc[2][4];
    #pragma unroll
    for (int ai = 0; ai < 2; ++ai)
        #pragma unroll
        for (int nt = 0; nt < 4; ++nt) sacc[ai][nt] = zero4;

    for (int hq = 0; hq < 4; ++hq) {
        f32x4 hacc[2][4];
        #pragma unroll
        for (int ai = 0; ai < 2; ++ai)
            #pragma unroll
            for (int nt = 0; nt < 4; ++nt) hacc[ai][nt] = zero4;
        #pragma unroll
        for (int kt = 0; kt < 2; ++kt)
            #pragma unroll
            for (int nt = 0; nt < 4; ++nt) {
                bf16x8 bf = pk16[(8 + hq * 8 + nt * 2 + kt) * 64 + lane];
                hacc[0][nt] = __builtin_amdgcn_mfma_f32_16x16x32_bf16(xf[0][kt], bf, hacc[0][nt], 0, 0, 0);
                hacc[1][nt] = __builtin_amdgcn_mfma_f32_16x16x32_bf16(xf[1][kt], bf, hacc[1][nt], 0, 0, 0);
            }
        // transpose Hq through wave-private LDS (overwrites X region: X already in regs)
        #pragma unroll
        for (int ai = 0; ai < 2; ++ai)
            #pragma unroll
            for (int nt = 0; nt < 4; ++nt) {
                int col = nt * 16 + c16;
                #pragma unroll
                for (int r = 0; r < 4; ++r)
                    xw[(ai * 16 + 4 * g + r) * XPAD + col] = f2bfu(fmaxf(hacc[ai][nt][r], 0.f));
            }
        __builtin_amdgcn_sched_barrier(0);
        asm volatile("s_waitcnt lgkmcnt(0)" ::: "memory");
        __builtin_amdgcn_sched_barrier(0);
        bf16x8 hf[2][2];
        #pragma unroll
        for (int ai = 0; ai < 2; ++ai)
            #pragma unroll
            for (int kt = 0; kt < 2; ++kt)
                hf[ai][kt] = *(const bf16x8*)&xw[(ai * 16 + c16) * XPAD + kt * 32 + g * 8];
        #pragma unroll
        for (int kt = 0; kt < 2; ++kt)
            #pragma unroll
            for (int nt = 0; nt < 4; ++nt) {
                bf16x8 bf = pk16[(40 + hq * 8 + nt * 2 + kt) * 64 + lane];
                sacc[0][nt] = __builtin_amdgcn_mfma_f32_16x16x32_bf16(hf[0][kt], bf, sacc[0][nt], 0, 0, 0);
                sacc[1][nt] = __builtin_amdgcn_mfma_f32_16x16x32_bf16(hf[1][kt], bf, sacc[1][nt], 0, 0, 0);
            }
    }

    // ---- epilogue: softmax over k (r in-reg, g via 2 shuffles), aggregate, store ----
    #pragma unroll
    for (int ai = 0; ai < 2; ++ai) {
        int a = a0 + ai;
        #pragma unroll
        for (int nt = 0; nt < 4; ++nt) {
            int d = nt * 16 + c16;
            float e0 = __expf(sacc[ai][nt][0]);
            float e1 = __expf(sacc[ai][nt][1]);
            float e2 = __expf(sacc[ai][nt][2]);
            float e3 = __expf(sacc[ai][nt][3]);
            float den = (e0 + e1) + (e2 + e3);
            unsigned v01 = vgp[ai][nt][0], v23 = vgp[ai][nt][1];
            float num = (e0 * bf2f((unsigned short)(v01 & 0xffff)) + e1 * bf2f((unsigned short)(v01 >> 16)))
                      + (e2 * bf2f((unsigned short)(v23 & 0xffff)) + e3 * bf2f((unsigned short)(v23 >> 16)));
            den += __shfl_xor(den, 16); num += __shfl_xor(num, 16);
            den += __shfl_xor(den, 32); num += __shfl_xor(num, 32);
            if (g == 0)
                out[(d * NPTS + n) * NA + a] = num / den;
        }
    }
}

extern "C" void kernel_launch(void* const* d_in, const int* in_sizes, int n_in,
                              void* d_out, int out_size, void* d_ws, size_t ws_size,
                              hipStream_t stream) {
    const float* xyz     = (const float*)d_in[0];
    const float* feats   = (const float*)d_in[1];
    const float* anchors = (const float*)d_in[2];
    const float* to_qkv  = (const float*)d_in[3];
    const float* pos1    = (const float*)d_in[4];
    const float* pos2    = (const float*)d_in[5];
    const float* am1     = (const float*)d_in[6];
    const float* am2     = (const float*)d_in[7];
    float* out = (float*)d_out;

    float* ws = (float*)d_ws;
    const int seg = NPTS * NA * DIM;
    float* qT = ws;
    float* kT = ws + seg;
    float* vT = ws + 2 * seg;
    int* nn = (int*)(ws + 3 * seg);
    unsigned short* pack = (unsigned short*)(ws + 3 * seg + NPTS * KNN);

    prep_kernel<<<256, 256, 0, stream>>>(feats, to_qkv, qT, pack, pos2, am1, am2, xyz, nn);
    attn_main<<<NPTS, 384, 0, stream>>>(xyz, pos1, anchors, pack, qT, kT, vT, nn, out);
}

// Round 6
// 76.330 us; speedup vs baseline: 1.1833x; 1.1833x over previous
//
#include <hip/hip_runtime.h>

#define NPTS 1024
#define DIM 64
#define KNN 16
#define NA 12
#define NCOL 192              // (a,k) rows, idx = a*16 + k
#define XPAD 76               // u16 row stride (stride 38 words -> conflict-free b128 frags)

typedef __attribute__((ext_vector_type(8))) short bf16x8;
typedef __attribute__((ext_vector_type(4))) float f32x4;

static __device__ inline unsigned short f2bfu(float x) {
    __bf16 b = (__bf16)x;                       // hw v_cvt (RNE)
    return __builtin_bit_cast(unsigned short, b);
}
static __device__ inline bf16x8 load8_cvt(const float* p) {
    f32x4 u = *(const f32x4*)p;
    f32x4 v = *(const f32x4*)(p + 4);
    bf16x8 r;
    r[0] = (short)f2bfu(u[0]); r[1] = (short)f2bfu(u[1]); r[2] = (short)f2bfu(u[2]); r[3] = (short)f2bfu(u[3]);
    r[4] = (short)f2bfu(v[0]); r[5] = (short)f2bfu(v[1]); r[6] = (short)f2bfu(v[2]); r[7] = (short)f2bfu(v[3]);
    return r;
}

// ---------------- prep kernel: 768 blocks x 256 thr (3 blocks/CU) ----------------
// every block: one 16-row m-tile of qkv GEMM (na rows n0..n0+15, all 192 cd cols)
// blocks <256: + KNN for 4 points;  blocks <72: + weight frag packing
__global__ __launch_bounds__(256) void prep_kernel(const float* __restrict__ feats,
                                                   const float* __restrict__ to_qkv,
                                                   float* __restrict__ qkvT,
                                                   unsigned short* __restrict__ pack,
                                                   const float* __restrict__ pos2,
                                                   const float* __restrict__ am1,
                                                   const float* __restrict__ am2,
                                                   const float* __restrict__ xyz,
                                                   int* __restrict__ idxout) {
    __shared__ unsigned short XT[16][72];   // feats^T [na][i] bf16 (one m-tile)
    __shared__ float px[NPTS], py[NPTS], pz[NPTS];
    const int b = blockIdx.x;
    const int t = threadIdx.x;
    const int n0 = b * 16;
    const bool do_knn = (b < 256);

    // ---- weight frag packing (blocks 0..71, one frag-set each) ----
    if (b < 72 && t < 64) {
        int s = b;
        int c16p = t & 15, gp = t >> 4;
        const float* src;
        if (s < 8) {
            int nt = s >> 1, kt = s & 1;
            src = pos2 + (nt * 16 + c16p) * 64 + kt * 32 + gp * 8;
        } else if (s < 40) {
            int u = s - 8, hq = u >> 3, nt = (u >> 1) & 3, kt = u & 1;
            src = am1 + (hq * 64 + nt * 16 + c16p) * 64 + kt * 32 + gp * 8;
        } else {
            int u = s - 40, hq = u >> 3, nt = (u >> 1) & 3, kt = u & 1;
            src = am2 + (nt * 16 + c16p) * 256 + hq * 64 + kt * 32 + gp * 8;
        }
        unsigned short* dst = pack + (s * 64 + t) * 8;
        #pragma unroll
        for (int e = 0; e < 8; ++e) dst[e] = f2bfu(src[e]);
    }

    // ---- stage ----
    if (do_knn) {
        for (int m = t; m < NPTS; m += 256) {
            px[m] = xyz[m];
            py[m] = xyz[NPTS + m];
            pz[m] = xyz[2 * NPTS + m];
        }
    }
    for (int e = t; e < 16 * 64; e += 256) {
        int c = e & 15, i = e >> 4;
        XT[c][i] = f2bfu(feats[i * (NPTS * NA) + n0 + c]);
    }
    __syncthreads();

    const int lane = t & 63, w = t >> 6, c16 = lane & 15, g = lane >> 4;

    // ---- qkv: D[na][cd] = feats^T @ to_qkv^T, one m-tile, wave w -> cd-tiles 3w..3w+2 ----
    {
        const f32x4 zero4 = {0.f, 0.f, 0.f, 0.f};
        f32x4 acc[3] = {zero4, zero4, zero4};
        #pragma unroll
        for (int kt = 0; kt < 2; ++kt) {
            bf16x8 af = *(const bf16x8*)&XT[c16][kt * 32 + g * 8];
            #pragma unroll
            for (int ni = 0; ni < 3; ++ni) {
                int cd = (w * 3 + ni) * 16 + c16;
                bf16x8 bfr = load8_cvt(to_qkv + cd * 64 + kt * 32 + g * 8);
                acc[ni] = __builtin_amdgcn_mfma_f32_16x16x32_bf16(af, bfr, acc[ni], 0, 0, 0);
            }
        }
        #pragma unroll
        for (int ni = 0; ni < 3; ++ni) {
            int cd = (w * 3 + ni) * 16 + c16;
            int c = cd >> 6, d = cd & 63;
            #pragma unroll
            for (int r = 0; r < 4; ++r) {
                int na = n0 + 4 * g + r;
                qkvT[c * (NPTS * NA * DIM) + na * 64 + d] = acc[ni][r];
            }
        }
    }

    // ---- knn: one wave per point, 4 points per block (blocks 0..255) ----
    if (do_knn) {
        const int n = b * 4 + w;
        const float xn = px[n], yn = py[n], zn = pz[n];
        const float sqn = xn * xn + yn * yn + zn * zn;
        float dd[16]; int id[16];
        #pragma unroll
        for (int j = 0; j < 16; ++j) {
            int m = j * 64 + lane;
            float xm = px[m], ym = py[m], zm = pz[m];
            float sqm = xm * xm + ym * ym + zm * zm;
            float dot = xn * xm + yn * ym + zn * zm;
            dd[j] = sqn + sqm - 2.f * dot;
            id[j] = m;
        }
        for (int r = 0; r < KNN; ++r) {
            float bd = 1e30f; int bi = 0x7fffffff;
            #pragma unroll
            for (int j = 0; j < 16; ++j)
                if (dd[j] < bd || (dd[j] == bd && id[j] < bi)) { bd = dd[j]; bi = id[j]; }
            #pragma unroll
            for (int mask = 1; mask < 64; mask <<= 1) {
                float od = __shfl_xor(bd, mask);
                int oi = __shfl_xor(bi, mask);
                if (od < bd || (od == bd && oi < bi)) { bd = od; bi = oi; }
            }
            if (lane == 0) idxout[n * KNN + r] = bi;
            #pragma unroll
            for (int j = 0; j < 16; ++j)
                if (id[j] == bi) dd[j] = 1e30f;
        }
    }
}

// ---------------- attn kernel: S^T orientation, activations = A-operand (round-4 verbatim) ----------------
// 8 waves: mw = wave&3 -> m-tiles {mw, mw+4, mw+8}; nw = wave>>2 -> n-tiles {2nw, 2nw+1}.
// C layout: lane(c16,g) reg r holds D[(a=mt, k=4g+r)][out = nt*16+c16].
__global__ __launch_bounds__(512, 4) void attn_main(const float* __restrict__ xyz,
                                                    const float* __restrict__ anchors,
                                                    const float* __restrict__ pos1,
                                                    const unsigned short* __restrict__ pack,
                                                    const float* __restrict__ qT,
                                                    const float* __restrict__ kT,
                                                    const float* __restrict__ vT,
                                                    const int* __restrict__ nn,
                                                    float* __restrict__ out) {
    __shared__ __align__(16) unsigned short XbT[NCOL][XPAD];   // pe1^T then X^T [(a,k)][h/d]
    __shared__ __align__(16) unsigned short HqT[NCOL][XPAD];   // H-quarter^T [(a,k)][h]
    __shared__ float relb[KNN][3];
    __shared__ float ab[108];
    __shared__ float gbuf[3][NCOL];
    __shared__ int nidx[KNN];

    const int n = blockIdx.x, t = threadIdx.x;
    const int lane = t & 63, wave = t >> 6;
    const int c16 = lane & 15, g = lane >> 4;
    const int mw = wave & 3;
    const int nw = wave >> 2;

    if (t < 108) ab[t] = anchors[t];
    if (t < KNN) {
        int m = nn[n * KNN + t];
        nidx[t] = m;
        relb[t][0] = xyz[n] - xyz[m];
        relb[t][1] = xyz[NPTS + n] - xyz[NPTS + m];
        relb[t][2] = xyz[2 * NPTS + n] - xyz[2 * NPTS + m];
    }
    __syncthreads();

    // ---- step 0: G[row][col] = (A_a @ rel_k)[row] ----
    for (int e = t; e < 3 * NCOL; e += 512) {
        int row = e / NCOL, col = e % NCOL;
        int a = col >> 4, k = col & 15;
        gbuf[row][col] = ab[a * 9 + row * 3 + 0] * relb[k][0]
                       + ab[a * 9 + row * 3 + 1] * relb[k][1]
                       + ab[a * 9 + row * 3 + 2] * relb[k][2];
    }
    __syncthreads();

    // ---- step 1: pe1^T = relu(P1 @ G)^T -> XbT ----
    {
        const float p10 = pos1[lane * 3 + 0], p11 = pos1[lane * 3 + 1], p12 = pos1[lane * 3 + 2];
        #pragma unroll
        for (int j = 0; j < 24; ++j) {
            int col = wave + 8 * j;
            float p = p10 * gbuf[0][col] + p11 * gbuf[1][col] + p12 * gbuf[2][col];
            XbT[col][lane] = f2bfu(p > 0.f ? p : 0.f);
        }
    }
    __syncthreads();

    const bf16x8* pk16 = (const bf16x8*)pack;
    const f32x4 zero4 = {0.f, 0.f, 0.f, 0.f};

    // ---- phase 0: pe^T = pe1^T @ P2^T ----
    f32x4 peacc[6] = {zero4, zero4, zero4, zero4, zero4, zero4};
    #pragma unroll
    for (int kt = 0; kt < 2; ++kt) {
        bf16x8 b0 = pk16[((2 * nw + 0) * 2 + kt) * 64 + lane];
        bf16x8 b1 = pk16[((2 * nw + 1) * 2 + kt) * 64 + lane];
        #pragma unroll
        for (int mi = 0; mi < 3; ++mi) {
            bf16x8 af = *(const bf16x8*)&XbT[(mw + 4 * mi) * 16 + c16][kt * 32 + g * 8];
            peacc[mi * 2 + 0] = __builtin_amdgcn_mfma_f32_16x16x32_bf16(af, b0, peacc[mi * 2 + 0], 0, 0, 0);
            peacc[mi * 2 + 1] = __builtin_amdgcn_mfma_f32_16x16x32_bf16(af, b1, peacc[mi * 2 + 1], 0, 0, 0);
        }
    }

    // ---- step 3: X = q - k_g + pe (regs), vg = v_g + pe (stays in regs!) ----
    float vgk[6][4], xreg[6][4];
    {
        const int m0 = nidx[4 * g + 0], m1 = nidx[4 * g + 1];
        const int m2 = nidx[4 * g + 2], m3 = nidx[4 * g + 3];
        #pragma unroll
        for (int mi = 0; mi < 3; ++mi) {
            int a = mw + 4 * mi;
            #pragma unroll
            for (int ni = 0; ni < 2; ++ni) {
                int tile = mi * 2 + ni;
                int d = (2 * nw + ni) * 16 + c16;
                float qv = qT[(n * NA + a) * DIM + d];
                int b0 = (m0 * NA + a) * DIM + d, b1 = (m1 * NA + a) * DIM + d;
                int b2 = (m2 * NA + a) * DIM + d, b3 = (m3 * NA + a) * DIM + d;
                xreg[tile][0] = qv - kT[b0] + peacc[tile][0]; vgk[tile][0] = vT[b0] + peacc[tile][0];
                xreg[tile][1] = qv - kT[b1] + peacc[tile][1]; vgk[tile][1] = vT[b1] + peacc[tile][1];
                xreg[tile][2] = qv - kT[b2] + peacc[tile][2]; vgk[tile][2] = vT[b2] + peacc[tile][2];
                xreg[tile][3] = qv - kT[b3] + peacc[tile][3]; vgk[tile][3] = vT[b3] + peacc[tile][3];
            }
        }
    }
    __syncthreads();   // phase-0 XbT reads complete before overwrite
    #pragma unroll
    for (int mi = 0; mi < 3; ++mi)
        #pragma unroll
        for (int ni = 0; ni < 2; ++ni) {
            int tile = mi * 2 + ni;
            int col = (2 * nw + ni) * 16 + c16;
            #pragma unroll
            for (int r = 0; r < 4; ++r)
                XbT[(mw + 4 * mi) * 16 + 4 * g + r][col] = f2bfu(xreg[tile][r]);
        }
    __syncthreads();

    // ---- 4 rounds: Hq^T = relu(X^T @ W1q^T); S^T += Hq^T @ W2q^T ----
    f32x4 sacc[6] = {zero4, zero4, zero4, zero4, zero4, zero4};
    for (int hq = 0; hq < 4; ++hq) {
        f32x4 hacc[6] = {zero4, zero4, zero4, zero4, zero4, zero4};
        #pragma unroll
        for (int kt = 0; kt < 2; ++kt) {
            bf16x8 b0 = pk16[(8 + (hq * 4 + 2 * nw + 0) * 2 + kt) * 64 + lane];
            bf16x8 b1 = pk16[(8 + (hq * 4 + 2 * nw + 1) * 2 + kt) * 64 + lane];
            #pragma unroll
            for (int mi = 0; mi < 3; ++mi) {
                bf16x8 af = *(const bf16x8*)&XbT[(mw + 4 * mi) * 16 + c16][kt * 32 + g * 8];
                hacc[mi * 2 + 0] = __builtin_amdgcn_mfma_f32_16x16x32_bf16(af, b0, hacc[mi * 2 + 0], 0, 0, 0);
                hacc[mi * 2 + 1] = __builtin_amdgcn_mfma_f32_16x16x32_bf16(af, b1, hacc[mi * 2 + 1], 0, 0, 0);
            }
        }
        #pragma unroll
        for (int mi = 0; mi < 3; ++mi)
            #pragma unroll
            for (int ni = 0; ni < 2; ++ni) {
                int tile = mi * 2 + ni;
                int col = (2 * nw + ni) * 16 + c16;
                #pragma unroll
                for (int r = 0; r < 4; ++r)
                    HqT[(mw + 4 * mi) * 16 + 4 * g + r][col] = f2bfu(fmaxf(hacc[tile][r], 0.f));
            }
        __syncthreads();
        #pragma unroll
        for (int kt = 0; kt < 2; ++kt) {
            bf16x8 b0 = pk16[(40 + hq * 8 + (2 * nw + 0) * 2 + kt) * 64 + lane];
            bf16x8 b1 = pk16[(40 + hq * 8 + (2 * nw + 1) * 2 + kt) * 64 + lane];
            #pragma unroll
            for (int mi = 0; mi < 3; ++mi) {
                bf16x8 af = *(const bf16x8*)&HqT[(mw + 4 * mi) * 16 + c16][kt * 32 + g * 8];
                sacc[mi * 2 + 0] = __builtin_amdgcn_mfma_f32_16x16x32_bf16(af, b0, sacc[mi * 2 + 0], 0, 0, 0);
                sacc[mi * 2 + 1] = __builtin_amdgcn_mfma_f32_16x16x32_bf16(af, b1, sacc[mi * 2 + 1], 0, 0, 0);
            }
        }
        __syncthreads();
    }

    // ---- epilogue: softmax over k = (4g+r); reg-sum over r, 2 shuffles over g ----
    #pragma unroll
    for (int mi = 0; mi < 3; ++mi) {
        int a = mw + 4 * mi;
        #pragma unroll
        for (int ni = 0; ni < 2; ++ni) {
            int tile = mi * 2 + ni;
            int d = (2 * nw + ni) * 16 + c16;
            float e0 = __expf(sacc[tile][0]);
            float e1 = __expf(sacc[tile][1]);
            float e2 = __expf(sacc[tile][2]);
            float e3 = __expf(sacc[tile][3]);
            float den = (e0 + e1) + (e2 + e3);
            float num = (e0 * vgk[tile][0] + e1 * vgk[tile][1]) + (e2 * vgk[tile][2] + e3 * vgk[tile][3]);
            den += __shfl_xor(den, 16); num += __shfl_xor(num, 16);
            den += __shfl_xor(den, 32); num += __shfl_xor(num, 32);
            if (g == 0)
                out[(d * NPTS + n) * NA + a] = num / den;
        }
    }
}

extern "C" void kernel_launch(void* const* d_in, const int* in_sizes, int n_in,
                              void* d_out, int out_size, void* d_ws, size_t ws_size,
                              hipStream_t stream) {
    const float* xyz     = (const float*)d_in[0];
    const float* feats   = (const float*)d_in[1];
    const float* anchors = (const float*)d_in[2];
    const float* to_qkv  = (const float*)d_in[3];
    const float* pos1    = (const float*)d_in[4];
    const float* pos2    = (const float*)d_in[5];
    const float* am1     = (const float*)d_in[6];
    const float* am2     = (const float*)d_in[7];
    float* out = (float*)d_out;

    float* ws = (float*)d_ws;
    const int seg = NPTS * NA * DIM;
    float* qT = ws;
    float* kT = ws + seg;
    float* vT = ws + 2 * seg;
    int* nn = (int*)(ws + 3 * seg);
    unsigned short* pack = (unsigned short*)(ws + 3 * seg + NPTS * KNN);

    prep_kernel<<<768, 256, 0, stream>>>(feats, to_qkv, qT, pack, pos2, am1, am2, xyz, nn);
    attn_main<<<NPTS, 512, 0, stream>>>(xyz, anchors, pos1, pack, qT, kT, vT, nn, out);
}